// Round 2
// baseline (103.936 us; speedup 1.0000x reference)
//
#include <hip/hip_runtime.h>
#include <hip/hip_bf16.h>

// memristor_dense: y[b,j] = sum_i A[i,2j]*2^(e[i,2j]*l[b,i]) - A[i,2j+1]*2^(e[i,2j+1]*l[b,i])
//   A[i,j] = 0.5*|w[i,j]| + max_w/18      (folds G, V_REF, 1/(K_V*k_G), G_MIN)
//   e[i,j] = log2(n_param[i,j]) + 1
//   l[b,i] = log2(2*clip(x[b,i],0,1))     (log2(0)=-inf -> exp2(-inf)=0 handles x==0 mask)
// shapes: x(128,1024), w_pos/w_neg(1024,512), b_pos/b_neg(512), n_param(1025,1024)

#define LOG2F(v)  __builtin_amdgcn_logf(v)    // v_log_f32: log2(x)
#define EXP2F(v)  __builtin_amdgcn_exp2f(v)   // v_exp_f32: 2^x

#define BB 16
#define BJ 16
#define KI 128
#define LROW (KI + 4)   // pad to 132 words: spreads banks, keeps 16B alignment for b128 reads

__global__ __launch_bounds__(256) void maxw_kernel(
    const float* __restrict__ w_pos, const float* __restrict__ w_neg,
    const float* __restrict__ b_pos, const float* __restrict__ b_neg,
    int n_w, int n_b, float* __restrict__ ws) {
  float m = 0.0f;
  int tid = blockIdx.x * blockDim.x + threadIdx.x;
  int stride = gridDim.x * blockDim.x;
  for (int i = tid; i < n_w; i += stride) {
    m = fmaxf(m, fabsf(w_pos[i]));
    m = fmaxf(m, fabsf(w_neg[i]));
  }
  if (tid < n_b) {
    m = fmaxf(m, fabsf(b_pos[tid]));
    m = fmaxf(m, fabsf(b_neg[tid]));
  }
  // wave64 reduce
  #pragma unroll
  for (int off = 32; off > 0; off >>= 1)
    m = fmaxf(m, __shfl_down(m, off, 64));
  __shared__ float sm[4];
  int lane = threadIdx.x & 63, wv = threadIdx.x >> 6;
  if (lane == 0) sm[wv] = m;
  __syncthreads();
  if (threadIdx.x == 0) {
    m = fmaxf(fmaxf(sm[0], sm[1]), fmaxf(sm[2], sm[3]));
    // all candidates >= 0 -> float bits compare correctly as int; ws pre-zeroed
    atomicMax((int*)ws, __float_as_int(m));
  }
}

__global__ __launch_bounds__(256) void memristor_kernel(
    const float* __restrict__ x, const float* __restrict__ w_pos,
    const float* __restrict__ w_neg, const float* __restrict__ b_pos,
    const float* __restrict__ b_neg, const float* __restrict__ n_param,
    const float* __restrict__ ws, float* __restrict__ y) {
  __shared__ float sL[BB * LROW];
  __shared__ float sA0[BJ * LROW];
  __shared__ float sA1[BJ * LROW];
  __shared__ float sE0[BJ * LROW];
  __shared__ float sE1[BJ * LROW];

  const float max_w = ws[0];
  const float c0 = max_w * (0.05f / 0.9f);   // G_MIN*V_REF/(K_V*k_G)

  const int j0 = blockIdx.x * BJ;   // 32 j-tiles
  const int b0 = blockIdx.y * BB;   // 8 b-tiles
  const int zt = blockIdx.z;        // 2-way i-split -> 512 blocks, 2/CU
  const int t  = threadIdx.x;
  const int jj = t & 15;
  const int bb = t >> 4;
  float accP = 0.0f, accN = 0.0f;

  const float2* np2 = (const float2*)n_param;

  for (int c = zt * 4; c < zt * 4 + 4; ++c) {
    const int i0 = c * KI;
    // stage x -> l = log2(2*clip(x))
    #pragma unroll
    for (int r = 0; r < (BB * KI) / 256; ++r) {
      int idx = r * 256 + t;
      int k  = idx & (KI - 1);
      int bl = idx >> 7;
      float v = x[(b0 + bl) * 1024 + i0 + k];
      v = fminf(fmaxf(v, 0.0f), 1.0f);
      sL[bl * LROW + k] = LOG2F(2.0f * v);
    }
    // stage params: A (folded coeff) and e (folded exponent), pos/neg columns
    #pragma unroll
    for (int r = 0; r < (BJ * KI) / 256; ++r) {
      int idx = r * 256 + t;
      int jl = idx & (BJ - 1);
      int il = idx >> 4;
      int gi = i0 + il;
      float wp = w_pos[gi * 512 + j0 + jl];
      float wn = w_neg[gi * 512 + j0 + jl];
      float2 np = np2[gi * 512 + j0 + jl];   // (n[i,2j], n[i,2j+1])
      sA0[jl * LROW + il] = fmaf(0.5f, fabsf(wp), c0);
      sA1[jl * LROW + il] = fmaf(0.5f, fabsf(wn), c0);
      sE0[jl * LROW + il] = LOG2F(np.x) + 1.0f;
      sE1[jl * LROW + il] = LOG2F(np.y) + 1.0f;
    }
    __syncthreads();
    const float* pL  = &sL[bb * LROW];
    const float* pA0 = &sA0[jj * LROW];
    const float* pA1 = &sA1[jj * LROW];
    const float* pE0 = &sE0[jj * LROW];
    const float* pE1 = &sE1[jj * LROW];
    #pragma unroll 4
    for (int k = 0; k < KI; ++k) {
      float l  = pL[k];
      float t0 = EXP2F(pE0[k] * l);
      float t1 = EXP2F(pE1[k] * l);
      accP = fmaf(pA0[k], t0, accP);
      accN = fmaf(pA1[k], t1, accN);
    }
    __syncthreads();
  }

  if (zt == 1) {
    // bias row i = 1024: inp = 1 -> l = 1 -> 2^(e*1)
    int jg = j0 + jj;
    float2 np = np2[1024 * 512 + jg];
    float a0 = fmaf(0.5f, fabsf(b_pos[jg]), c0);
    float a1 = fmaf(0.5f, fabsf(b_neg[jg]), c0);
    accP = fmaf(a0, EXP2F(LOG2F(np.x) + 1.0f), accP);
    accN = fmaf(a1, EXP2F(LOG2F(np.y) + 1.0f), accN);
  }

  atomicAdd(&y[(b0 + bb) * 512 + (j0 + jj)], accP - accN);
}

extern "C" void kernel_launch(void* const* d_in, const int* in_sizes, int n_in,
                              void* d_out, int out_size, void* d_ws, size_t ws_size,
                              hipStream_t stream) {
  const float* x       = (const float*)d_in[0];
  const float* w_pos   = (const float*)d_in[1];
  const float* w_neg   = (const float*)d_in[2];
  const float* b_pos   = (const float*)d_in[3];
  const float* b_neg   = (const float*)d_in[4];
  const float* n_param = (const float*)d_in[5];
  float* y   = (float*)d_out;
  float* wsf = (float*)d_ws;

  (void)hipMemsetAsync(d_ws, 0, 4, stream);                       // maxw accumulator
  (void)hipMemsetAsync(d_out, 0, (size_t)out_size * 4, stream);   // atomicAdd target

  maxw_kernel<<<dim3(256), dim3(256), 0, stream>>>(
      w_pos, w_neg, b_pos, b_neg, in_sizes[1], in_sizes[3], wsf);

  memristor_kernel<<<dim3(32, 8, 2), dim3(256), 0, stream>>>(
      x, w_pos, w_neg, b_pos, b_neg, n_param, wsf, y);
}

// Round 3
// 93.816 us; speedup vs baseline: 1.1079x; 1.1079x over previous
//
#include <hip/hip_runtime.h>
#include <hip/hip_bf16.h>

// memristor_dense: y[b,j] = sum_i A[i,2j]*2^(e[i,2j]*l[b,i]) - A[i,2j+1]*2^(e[i,2j+1]*l[b,i])
//   A[i,j] = 0.5*|w[i,j]| + max_w/18      (folds G, V_REF, 1/(K_V*k_G), G_MIN)
//   e[i,j] = log2(n_param[i,j]) + 1
//   l[b,i] = log2(2*clip(x[b,i],0,1))     (log2(0)=-inf -> exp2(-inf)=0 handles x==0 mask)
// shapes: x(128,1024), w_pos/w_neg(1024,512), b_pos/b_neg(512), n_param(1025,1024)
//
// R2 -> R3: (1) params packed as float4{A0,E0,A1,E1} in LDS -> 1 ds_read_b128 + 1
// broadcast b32 per pair instead of 5 b32 (LDS-issue-bound -> trans/VALU-bound);
// (2) 4->2 dispatches: setup kernel zeroes d_out + plain-store max partials (no
// memsets, no atomics); (3) z-split 4 -> 16 waves/CU.

#define LOG2F(v)  __builtin_amdgcn_logf(v)    // v_log_f32: log2(x)
#define EXP2F(v)  __builtin_amdgcn_exp2f(v)   // v_exp_f32: 2^x

#define NJ 16        // jpairs per block
#define NB 16        // batch rows per block
#define KI 64        // k-chunk
#define KROW4 65     // sP row stride in float4 (pad: bank offset 4 -> 2-way = free)
#define LROW 68      // sL row stride in floats

#define NPART 32     // max-partial blocks

__global__ __launch_bounds__(256) void setup_kernel(
    const float* __restrict__ w_pos, const float* __restrict__ w_neg,
    const float* __restrict__ b_pos, const float* __restrict__ b_neg,
    float* __restrict__ y, float* __restrict__ ws) {
  const int t = threadIdx.x, blk = blockIdx.x;
  // zero d_out: 65536 floats = 16384 float4, 512 per block
  float4 z4 = make_float4(0.f, 0.f, 0.f, 0.f);
  float4* y4 = (float4*)y;
  y4[blk * 512 + t]       = z4;
  y4[blk * 512 + 256 + t] = z4;
  // partial |w| max: 131072 float4 per array, 4096 per block, 16 per thread
  const float4* wp4 = (const float4*)w_pos;
  const float4* wn4 = (const float4*)w_neg;
  float m = 0.0f;
  #pragma unroll 4
  for (int r = 0; r < 16; ++r) {
    int i = blk * 4096 + r * 256 + t;
    float4 a = wp4[i], b = wn4[i];
    m = fmaxf(m, fmaxf(fmaxf(fabsf(a.x), fabsf(a.y)), fmaxf(fabsf(a.z), fabsf(a.w))));
    m = fmaxf(m, fmaxf(fmaxf(fabsf(b.x), fabsf(b.y)), fmaxf(fabsf(b.z), fabsf(b.w))));
  }
  if (blk == 0) {
    m = fmaxf(m, fmaxf(fabsf(b_pos[t]), fabsf(b_pos[t + 256])));
    m = fmaxf(m, fmaxf(fabsf(b_neg[t]), fabsf(b_neg[t + 256])));
  }
  #pragma unroll
  for (int off = 32; off > 0; off >>= 1)
    m = fmaxf(m, __shfl_down(m, off, 64));
  __shared__ float sm[4];
  int lane = t & 63, wv = t >> 6;
  if (lane == 0) sm[wv] = m;
  __syncthreads();
  if (t == 0)
    ws[blk] = fmaxf(fmaxf(sm[0], sm[1]), fmaxf(sm[2], sm[3]));  // plain store, no init needed
}

__global__ __launch_bounds__(256) void memristor_kernel(
    const float* __restrict__ x, const float* __restrict__ w_pos,
    const float* __restrict__ w_neg, const float* __restrict__ b_pos,
    const float* __restrict__ b_neg, const float* __restrict__ n_param,
    const float* __restrict__ ws, float* __restrict__ y) {
  __shared__ float4 sP[NJ * KROW4];
  __shared__ float  sL[NB * LROW];

  // reduce the 32 max partials (uniform, once per block)
  float mw = 0.0f;
  #pragma unroll
  for (int i = 0; i < NPART; ++i) mw = fmaxf(mw, ws[i]);
  const float c0 = mw * (0.05f / 0.9f);   // G_MIN*V_REF/(K_V*k_G) = max_w/18

  const int j0 = blockIdx.x * NJ;   // 32 j-tiles
  const int b0 = blockIdx.y * NB;   // 8 b-tiles
  const int zt = blockIdx.z;        // 4-way i-split: rows [zt*256, zt*256+256)
  const int t  = threadIdx.x;
  const int jj = t & 15;
  const int bb = t >> 4;
  float accP = 0.0f, accN = 0.0f;

  const float2* np2 = (const float2*)n_param;

  for (int c = 0; c < 4; ++c) {
    const int i0 = zt * 256 + c * KI;
    // stage x -> l = log2(2*clip(x)) : 16 rows x 64
    #pragma unroll
    for (int r = 0; r < (NB * KI) / 256; ++r) {
      int idx = r * 256 + t;
      int k  = idx & (KI - 1);
      int bl = idx >> 6;
      float v = x[(b0 + bl) * 1024 + i0 + k];
      v = fminf(fmaxf(v, 0.0f), 1.0f);
      sL[bl * LROW + k] = LOG2F(2.0f * v);
    }
    // stage params as float4 {A0, E0, A1, E1} : 16 jpairs x 64 k
    #pragma unroll
    for (int r = 0; r < (NJ * KI) / 256; ++r) {
      int idx = r * 256 + t;
      int jl = idx & (NJ - 1);
      int il = idx >> 4;
      int gi = i0 + il;
      float wp = w_pos[gi * 512 + j0 + jl];
      float wn = w_neg[gi * 512 + j0 + jl];
      float2 np = np2[gi * 512 + j0 + jl];   // (n[i,2j], n[i,2j+1])
      sP[jl * KROW4 + il] = make_float4(
          fmaf(0.5f, fabsf(wp), c0), LOG2F(np.x) + 1.0f,
          fmaf(0.5f, fabsf(wn), c0), LOG2F(np.y) + 1.0f);
    }
    __syncthreads();
    const float4* pP = &sP[jj * KROW4];
    const float*  pL = &sL[bb * LROW];
    #pragma unroll 8
    for (int k = 0; k < KI; ++k) {
      float4 p = pP[k];
      float l  = pL[k];
      accP = fmaf(p.x, EXP2F(p.y * l), accP);
      accN = fmaf(p.z, EXP2F(p.w * l), accN);
    }
    __syncthreads();
  }

  if (zt == 3) {
    // bias row i = 1024: inp = 1 -> vr = 2 -> 2^e
    int jg = j0 + jj;
    float2 np = np2[1024 * 512 + jg];
    float a0 = fmaf(0.5f, fabsf(b_pos[jg]), c0);
    float a1 = fmaf(0.5f, fabsf(b_neg[jg]), c0);
    accP = fmaf(a0, EXP2F(LOG2F(np.x) + 1.0f), accP);
    accN = fmaf(a1, EXP2F(LOG2F(np.y) + 1.0f), accN);
  }

  atomicAdd(&y[(b0 + bb) * 512 + (j0 + jj)], accP - accN);
}

extern "C" void kernel_launch(void* const* d_in, const int* in_sizes, int n_in,
                              void* d_out, int out_size, void* d_ws, size_t ws_size,
                              hipStream_t stream) {
  const float* x       = (const float*)d_in[0];
  const float* w_pos   = (const float*)d_in[1];
  const float* w_neg   = (const float*)d_in[2];
  const float* b_pos   = (const float*)d_in[3];
  const float* b_neg   = (const float*)d_in[4];
  const float* n_param = (const float*)d_in[5];
  float* y   = (float*)d_out;
  float* wsf = (float*)d_ws;

  setup_kernel<<<dim3(NPART), dim3(256), 0, stream>>>(
      w_pos, w_neg, b_pos, b_neg, y, wsf);

  memristor_kernel<<<dim3(32, 8, 4), dim3(256), 0, stream>>>(
      x, w_pos, w_neg, b_pos, b_neg, n_param, wsf, y);
}